// Round 10
// baseline (59.852 us; speedup 1.0000x reference)
//
#include <hip/hip_runtime.h>
#include <hip/hip_bf16.h>

// AdaGuidedFilter: x:(4,64,256,256) f32 -> out same shape.
// out = x * (A*x + (1-A)*mean), A = var/(var+eps),
// mean/var from 11x11 zero-padded box sums normalized by in-window count.
//
// R9b: R6's launch shape (256-thread blocks, 1 barrier, many short blocks)
// + R8's 2-cols/thread instruction reduction. Each block = 2 independent
// 8-row strips (half = t>>7, wave-uniform). 32 KB LDS -> 5 blocks/CU.
// Full XOR swizzle p ^ ((p>>3)&7) ^ (r&7): bank = f(d'^seg^lr) -> all 8
// residues used (R8's lr-only swizzle was an 8-way conflict across segs).
// Nontemporal output stores (native vec type - HIP float4 rejected by the
// builtin) keep the input L3-resident.

#define RAD    5
#define KW     11
#define IMG_H  256
#define IMG_W  256
#define TILE_H 8
#define IN_H   (TILE_H + 2 * RAD)   // 18
#define PSTRIPS 16                  // pair-strips (2 strips each) per image
#define NBLK   (256 * PSTRIPS)      // 4096
#define EPS_F  0.01f

#define SW(p, r) (((p) ^ (((p) >> 3) & 7) ^ ((r) & 7)))

typedef float f32x4 __attribute__((ext_vector_type(4)));

__device__ __forceinline__ float epil(float S, float S2, float inv, float xq) {
    const float mean = S * inv;
    const float m2   = S2 * inv;
    const float var  = fmaf(-mean, mean, m2);
    const float A    = var * __builtin_amdgcn_rcpf(var + EPS_F);
    return xq * fmaf(A, xq - mean, mean);
}

template<bool ROWCHECK>
__device__ __forceinline__ void run2(const float* __restrict__ xim,
                                     float* __restrict__ oim,
                                     float4* __restrict__ vs4,
                                     int ps, int t) {
    const int half  = t >> 7;            // wave-uniform
    const int th    = t & 127;
    const int strip = ps * 2 + half;     // 0..31
    const int row0  = strip * TILE_H - RAD;
    float4* __restrict__ vb = vs4 + half * (TILE_H * 128);

    // ---- phase 1: one float2 column-pair per thread, vertical sliding sums ----
    {
        const int cc0 = th << 1;
        float2 xr[IN_H];
        #pragma unroll
        for (int li = 0; li < IN_H; ++li) {
            const int g = row0 + li;     // wave-uniform bound check
            if (!ROWCHECK || (g >= 0 && g < IMG_H))
                xr[li] = *reinterpret_cast<const float2*>(xim + (size_t)g * IMG_W + cc0);
            else
                xr[li] = make_float2(0.0f, 0.0f);
        }

        float s0 = 0.f, s20 = 0.f, s1 = 0.f, s21 = 0.f;
        #pragma unroll
        for (int li = 0; li < KW; ++li) {
            s0 += xr[li].x; s20 = fmaf(xr[li].x, xr[li].x, s20);
            s1 += xr[li].y; s21 = fmaf(xr[li].y, xr[li].y, s21);
        }
        #pragma unroll
        for (int r = 0; r < TILE_H; ++r) {
            vb[(r << 7) | SW(th, r)] = make_float4(s0, s20, s1, s21);
            if (r < TILE_H - 1) {
                const float ax = xr[r + KW].x, bx = xr[r].x;
                const float ay = xr[r + KW].y, by = xr[r].y;
                s0 += ax - bx;  s20 = fmaf(ax, ax, fmaf(-bx, bx, s20));
                s1 += ay - by;  s21 = fmaf(ay, ay, fmaf(-by, by, s21));
            }
        }
    }
    __syncthreads();

    // ---- phase 2: one row x 16 px per thread (8 pairs) ----
    const int lr  = th & 7;
    const int seg = th >> 3;    // 0..15
    const int p0  = seg << 3;
    const int c0  = p0 << 1;
    const int gr  = strip * TILE_H + lr;

    // epilogue x (cache-resident after phase 1), issued before LDS reads
    float xv[16];
    {
        const float4* xp = reinterpret_cast<const float4*>(xim + (size_t)gr * IMG_W + c0);
        #pragma unroll
        for (int j = 0; j < 4; ++j) {
            const float4 q = xp[j];
            xv[4*j+0] = q.x; xv[4*j+1] = q.y; xv[4*j+2] = q.z; xv[4*j+3] = q.w;
        }
    }

    const int rlo = (gr - RAD < 0) ? 0 : gr - RAD;
    const int rhi = (gr + RAD > IMG_H - 1) ? IMG_H - 1 : gr + RAD;
    const float rcnt = (float)(rhi - rlo + 1);

    float o[16];
    if (seg >= 1 && seg <= 14) {
        // interior: 6-pair register window, slide 2 px per single b128 read
        float4 w0 = vb[(lr << 7) | SW(p0 - 3, lr)];
        float4 w1 = vb[(lr << 7) | SW(p0 - 2, lr)];
        float4 w2 = vb[(lr << 7) | SW(p0 - 1, lr)];
        float4 w3 = vb[(lr << 7) | SW(p0    , lr)];
        float4 w4 = vb[(lr << 7) | SW(p0 + 1, lr)];
        float4 w5 = vb[(lr << 7) | SW(p0 + 2, lr)];
        float Fs  = (w1.x + w1.z) + (w2.x + w2.z) + (w3.x + w3.z) + (w4.x + w4.z) + (w5.x + w5.z);
        float Fs2 = (w1.y + w1.w) + (w2.y + w2.w) + (w3.y + w3.w) + (w4.y + w4.w) + (w5.y + w5.w);
        const float inv = __builtin_amdgcn_rcpf(rcnt * 11.0f);

        #pragma unroll
        for (int g = 0; g < 8; ++g) {
            const float Se  = Fs  + w0.z;   // even px: full pairs + odd(p-3)
            const float Se2 = Fs2 + w0.w;
            const float4 nw = vb[(lr << 7) | SW(p0 + g + 3, lr)];
            const float So  = Fs  + nw.x;   // odd px: full pairs + even(p+3)
            const float So2 = Fs2 + nw.y;
            o[2*g]   = epil(Se, Se2, inv, xv[2*g]);
            o[2*g+1] = epil(So, So2, inv, xv[2*g+1]);
            Fs  += (nw.x + nw.z) - (w1.x + w1.z);
            Fs2 += (nw.y + nw.w) - (w1.y + w1.w);
            w0 = w1; w1 = w2; w2 = w3; w3 = w4; w4 = w5; w5 = nw;
        }
    } else {
        // edge segments (0, 15): bounds-checked scalar sliding window
        const float2* vb2 = reinterpret_cast<const float2*>(vb);
        float s = 0.f, s2 = 0.f;
        #pragma unroll
        for (int dd = -RAD; dd <= RAD; ++dd) {
            const int cc = c0 + dd;
            if (cc >= 0 && cc < IMG_W) {
                const float2 v = vb2[((((lr << 7) | SW(cc >> 1, lr)) << 1) | (cc & 1))];
                s += v.x; s2 += v.y;
            }
        }
        #pragma unroll
        for (int i = 0; i < 16; ++i) {
            const int c   = c0 + i;
            const int wlo = (c - RAD < 0) ? 0 : c - RAD;
            const int whi = (c + RAD > IMG_W - 1) ? IMG_W - 1 : c + RAD;
            const float inv = __builtin_amdgcn_rcpf(rcnt * (float)(whi - wlo + 1));
            o[i] = epil(s, s2, inv, xv[i]);
            if (i < 15) {
                const int ca = c + RAD + 1;
                const int cs = c - RAD;
                if (ca < IMG_W) {
                    const float2 v = vb2[((((lr << 7) | SW(ca >> 1, lr)) << 1) | (ca & 1))];
                    s += v.x; s2 += v.y;
                }
                if (cs >= 0) {
                    const float2 v = vb2[((((lr << 7) | SW(cs >> 1, lr)) << 1) | (cs & 1))];
                    s -= v.x; s2 -= v.y;
                }
            }
        }
    }

    // nontemporal stores: don't evict the L3-resident input with output stream
    f32x4* orow = reinterpret_cast<f32x4*>(oim + (size_t)gr * IMG_W + c0);
    #pragma unroll
    for (int j = 0; j < 4; ++j) {
        f32x4 v; v.x = o[4*j+0]; v.y = o[4*j+1]; v.z = o[4*j+2]; v.w = o[4*j+3];
        __builtin_nontemporal_store(v, orow + j);
    }
}

__global__ __launch_bounds__(256)
void AdaGuidedFilter_17686675325295_kernel(const float* __restrict__ x,
                                           float* __restrict__ out) {
    __shared__ float4 vs4[2 * TILE_H * 128];   // 32768 B -> 5 blocks/CU (20 waves)

    // XCD-chunked swizzle (4096 % 8 == 0 -> bijective)
    const int d   = blockIdx.x;
    const int L   = (d & 7) * (NBLK / 8) + (d >> 3);
    const int img = L >> 4;              // 0..255
    const int ps  = L & (PSTRIPS - 1);   // 0..15

    const float* __restrict__ xim = x   + (size_t)img * (IMG_H * IMG_W);
    float* __restrict__       oim = out + (size_t)img * (IMG_H * IMG_W);

    if (ps != 0 && ps != PSTRIPS - 1)
        run2<false>(xim, oim, vs4, ps, threadIdx.x);
    else
        run2<true>(xim, oim, vs4, ps, threadIdx.x);
}

extern "C" void kernel_launch(void* const* d_in, const int* in_sizes, int n_in,
                              void* d_out, int out_size, void* d_ws, size_t ws_size,
                              hipStream_t stream) {
    (void)in_sizes; (void)n_in; (void)d_ws; (void)ws_size; (void)out_size;
    const float* x = (const float*)d_in[0];
    float* out = (float*)d_out;
    dim3 grid(NBLK);     // 4096 blocks
    dim3 block(256);
    AdaGuidedFilter_17686675325295_kernel<<<grid, block, 0, stream>>>(x, out);
}

// Round 11
// 31.339 us; speedup vs baseline: 1.9098x; 1.9098x over previous
//
#include <hip/hip_runtime.h>
#include <hip/hip_bf16.h>

// AdaGuidedFilter: x:(4,64,256,256) f32 -> out same shape.
// out = x * (A*x + (1-A)*mean), A = var/(var+eps),
// mean/var from 11x11 zero-padded box sums normalized by in-window count.
//
// R10: R6 structure (TILE_H=8, 16 KB LDS, c^r swizzle, 8192 blocks, 256 thr,
// one barrier, regular stores) with instruction cuts:
//  - phase 1 done by 128 pair-threads (float2 loads, packed f32x2 sums,
//    one b128 LDS write/row); waves 2-3 skip to barrier.
//  - packed-pair interior epilogue (f32x2 -> v_pk_*_f32).
//  - xv prefetched before the barrier.
// NO nontemporal stores (R9: +40 MB write amplification). No forced
// launch-bounds min-waves (R4/R5: VGPR clamp -> spill).

#define RAD    5
#define KW     11
#define IMG_H  256
#define IMG_W  256
#define TILE_H 8
#define IN_H   (TILE_H + 2 * RAD)   // 18
#define STRIPS (IMG_H / TILE_H)     // 32
#define NBLK   (256 * STRIPS)       // 8192
#define EPS_F  0.01f

typedef float f32x2 __attribute__((ext_vector_type(2)));

__global__ __launch_bounds__(256)
void AdaGuidedFilter_17686675325295_kernel(const float* __restrict__ x,
                                           float* __restrict__ out) {
    __shared__ float2 vsum[TILE_H * IMG_W];   // 16384 B

    // XCD-chunked swizzle (8192 % 8 == 0 -> bijective)
    const int d     = blockIdx.x;
    const int L     = (d & 7) * (NBLK / 8) + (d >> 3);
    const int img   = L >> 5;            // 0..255
    const int strip = L & (STRIPS - 1);  // 0..31
    const int t     = threadIdx.x;

    const float* __restrict__ xim = x   + (size_t)img * (IMG_H * IMG_W);
    float* __restrict__       oim = out + (size_t)img * (IMG_H * IMG_W);

    const int row0 = strip * TILE_H - RAD;
    const bool rowcheck = (strip == 0) || (strip == STRIPS - 1);

    // phase-2 coordinates
    const int lr  = t & 7;      // local row
    const int seg = t >> 3;     // 0..31, 8 columns each
    const int c0  = seg * 8;
    const int gr  = strip * TILE_H + lr;

    float xv[8];
    if (t >= 128) {
        // idle-in-phase-1 waves: prefetch epilogue x now
        const float4* p = reinterpret_cast<const float4*>(xim + (size_t)gr * IMG_W + c0);
        const float4 q0 = p[0], q1 = p[1];
        xv[0]=q0.x; xv[1]=q0.y; xv[2]=q0.z; xv[3]=q0.w;
        xv[4]=q1.x; xv[5]=q1.y; xv[6]=q1.z; xv[7]=q1.w;
    }

    // ---- phase 1: 128 pair-threads, packed vertical sliding sums ----
    if (t < 128) {
        const int cc0 = t << 1;
        f32x2 xr[IN_H];
        if (!rowcheck) {
            #pragma unroll
            for (int li = 0; li < IN_H; ++li)
                xr[li] = *reinterpret_cast<const f32x2*>(xim + (size_t)(row0 + li) * IMG_W + cc0);
        } else {
            #pragma unroll
            for (int li = 0; li < IN_H; ++li) {
                const int g = row0 + li;   // wave-uniform check
                if (g >= 0 && g < IMG_H)
                    xr[li] = *reinterpret_cast<const f32x2*>(xim + (size_t)g * IMG_W + cc0);
                else
                    xr[li] = (f32x2){0.0f, 0.0f};
            }
        }

        f32x2 s = {0.0f, 0.0f}, s2 = {0.0f, 0.0f};
        #pragma unroll
        for (int li = 0; li < KW; ++li) {
            s += xr[li];
            s2 = __builtin_elementwise_fma(xr[li], xr[li], s2);
        }

        float4* vs4 = reinterpret_cast<float4*>(vsum);
        #pragma unroll
        for (int r = 0; r < TILE_H; ++r) {
            // float2-idx of col c is (r<<8)|(c^r); cols (cc0, cc0+1) share the
            // float4 slot (r<<7)|((cc0^r)>>1), order swapped when r is odd.
            const int bi = (r << 7) | ((cc0 ^ r) >> 1);
            if ((r & 1) == 0) vs4[bi] = make_float4(s.x, s2.x, s.y, s2.y);
            else              vs4[bi] = make_float4(s.y, s2.y, s.x, s2.x);
            if (r < TILE_H - 1) {
                const f32x2 a = xr[r + KW], b = xr[r];
                s  += a - b;
                s2  = __builtin_elementwise_fma(a, a,
                        __builtin_elementwise_fma(-b, b, s2));
            }
        }

        // worker waves: xv prefetch at phase-1 end, latency hides under barrier
        const float4* p = reinterpret_cast<const float4*>(xim + (size_t)gr * IMG_W + c0);
        const float4 q0 = p[0], q1 = p[1];
        xv[0]=q0.x; xv[1]=q0.y; xv[2]=q0.z; xv[3]=q0.w;
        xv[4]=q1.x; xv[5]=q1.y; xv[6]=q1.z; xv[7]=q1.w;
    }
    __syncthreads();

    // ---- phase 2: horizontal sliding window + packed epilogue ----
    const int rlo = (gr - RAD < 0) ? 0 : gr - RAD;
    const int rhi = (gr + RAD > IMG_H - 1) ? IMG_H - 1 : gr + RAD;
    const float rcnt = (float)(rhi - rlo + 1);

    float o[8];
    if (seg >= 1 && seg <= 30) {
        // interior: constant window width 11 -> one rcp for mean-normalizer
        float s = 0.0f, s2 = 0.0f;
        #pragma unroll
        for (int dd = -RAD; dd <= RAD; ++dd) {
            const float2 v = vsum[(lr << 8) | ((c0 + dd) ^ lr)];
            s += v.x; s2 += v.y;
        }
        const float inv = __builtin_amdgcn_rcpf(rcnt * 11.0f);
        const f32x2 inv2  = {inv, inv};
        const f32x2 eps2  = {EPS_F, EPS_F};

        #pragma unroll
        for (int g = 0; g < 4; ++g) {
            const int ce = c0 + 2 * g;
            // slide even -> odd pixel
            const float2 va = vsum[(lr << 8) | ((ce + RAD + 1) ^ lr)];
            const float2 vb = vsum[(lr << 8) | ((ce - RAD) ^ lr)];
            const float so  = s  + va.x - vb.x;
            const float s2o = s2 + va.y - vb.y;
            // packed epilogue on the pair
            const f32x2 SS   = {s, so};
            const f32x2 SS2  = {s2, s2o};
            const f32x2 mean = SS * inv2;
            const f32x2 m2   = SS2 * inv2;
            const f32x2 var  = __builtin_elementwise_fma(-mean, mean, m2);
            const f32x2 den  = var + eps2;
            const f32x2 rr   = {__builtin_amdgcn_rcpf(den.x), __builtin_amdgcn_rcpf(den.y)};
            const f32x2 A    = var * rr;
            const f32x2 xq   = {xv[2*g], xv[2*g+1]};
            const f32x2 xm   = xq - mean;
            const f32x2 tt   = __builtin_elementwise_fma(A, xm, mean);
            const f32x2 oo   = xq * tt;
            o[2*g]   = oo.x;
            o[2*g+1] = oo.y;
            // slide odd -> next even pixel
            if (g < 3) {
                const float2 va2 = vsum[(lr << 8) | ((ce + RAD + 2) ^ lr)];
                const float2 vb2 = vsum[(lr << 8) | ((ce - RAD + 1) ^ lr)];
                s  = so  + va2.x - vb2.x;
                s2 = s2o + va2.y - vb2.y;
            }
        }
    } else {
        // edge segments (0, 31): bounds-checked scalar sliding window
        float s = 0.0f, s2 = 0.0f;
        #pragma unroll
        for (int dd = -RAD; dd <= RAD; ++dd) {
            const int cc = c0 + dd;
            if (cc >= 0 && cc < IMG_W) {
                const float2 v = vsum[(lr << 8) | (cc ^ lr)];
                s += v.x; s2 += v.y;
            }
        }
        #pragma unroll
        for (int i = 0; i < 8; ++i) {
            const int c   = c0 + i;
            const int wlo = (c - RAD < 0) ? 0 : c - RAD;
            const int whi = (c + RAD > IMG_W - 1) ? IMG_W - 1 : c + RAD;
            const float inv  = __builtin_amdgcn_rcpf(rcnt * (float)(whi - wlo + 1));
            const float mean = s * inv;
            const float m2   = s2 * inv;
            const float var  = fmaf(-mean, mean, m2);
            const float A    = var * __builtin_amdgcn_rcpf(var + EPS_F);
            const float xq   = xv[i];
            o[i] = xq * fmaf(A, xq - mean, mean);
            if (i < 7) {
                const int ca = c + RAD + 1;
                const int cs = c - RAD;
                if (ca < IMG_W) { const float2 v = vsum[(lr << 8) | (ca ^ lr)]; s += v.x; s2 += v.y; }
                if (cs >= 0)    { const float2 v = vsum[(lr << 8) | (cs ^ lr)]; s -= v.x; s2 -= v.y; }
            }
        }
    }

    float4* orow = reinterpret_cast<float4*>(oim + (size_t)gr * IMG_W + c0);
    orow[0] = make_float4(o[0], o[1], o[2], o[3]);
    orow[1] = make_float4(o[4], o[5], o[6], o[7]);
}

extern "C" void kernel_launch(void* const* d_in, const int* in_sizes, int n_in,
                              void* d_out, int out_size, void* d_ws, size_t ws_size,
                              hipStream_t stream) {
    (void)in_sizes; (void)n_in; (void)d_ws; (void)ws_size; (void)out_size;
    const float* x = (const float*)d_in[0];
    float* out = (float*)d_out;
    dim3 grid(NBLK);     // 8192 blocks
    dim3 block(256);
    AdaGuidedFilter_17686675325295_kernel<<<grid, block, 0, stream>>>(x, out);
}